// Round 1
// baseline (197.866 us; speedup 1.0000x reference)
//
#include <hip/hip_runtime.h>
#include <hip/hip_bf16.h>

// IterNorm: x(64,256,56,56) fp32 -> whiten per 64-ch group (4 groups) via
// Newton-Schulz (T=5), then *weight + bias.
//
// Pass 1: per-group gram matrix + per-channel sums (bf16 MFMA, atomically reduced)
// Pass 2: Sigma -> Sn -> 5 NS iters -> wm (split hi/lo bf16 MFMA, 4 blocks)
// Pass 3: out = wm @ (x - mu) * w + b   (bf16 MFMA, wm in hi/lo regs)

#define B_    64
#define C_    256
#define HW_   3136
#define G_    4
#define NC_   64
#define M_    (B_*HW_)          // 200704
#define EPS_  1e-5f
#define TIT_  5

typedef __attribute__((ext_vector_type(8))) short  s16x8;
typedef __attribute__((ext_vector_type(4))) float  f32x4;

#define MFMA_(A,Bv,Cc) Cc = __builtin_amdgcn_mfma_f32_16x16x32_bf16(A, Bv, Cc, 0, 0, 0)

__device__ __forceinline__ unsigned short f2bf(float f){
  union{ float f; unsigned int u; } c; c.f = f;
  unsigned int u = c.u;
  u = u + 0x7FFFu + ((u >> 16) & 1u);
  return (unsigned short)(u >> 16);
}
__device__ __forceinline__ float bf2f(unsigned short h){
  union{ unsigned int u; float f; } c; c.u = ((unsigned int)h) << 16;
  return c.f;
}
// XOR swizzle: rows are 128B (64 bf16); spread 16-row column reads across banks.
__device__ __forceinline__ int swz(int off, int row){
  return off ^ ((row & 7) << 4) ^ (((row >> 3) & 3) << 5);
}
__device__ __forceinline__ s16x8 ld_frag(const unsigned short* base, int row, int kbyte){
  return *(const s16x8*)((const char*)base + swz(row*128 + kbyte, row));
}
__device__ __forceinline__ void st_h(unsigned short* base, int row, int col, unsigned short v){
  *(unsigned short*)((char*)base + swz(row*128 + col*2, row)) = v;
}
__device__ __forceinline__ unsigned short ld_h(const unsigned short* base, int row, int col){
  return *(const unsigned short*)((const char*)base + swz(row*128 + col*2, row));
}

// ---------------- Pass 1: gram + sums ----------------
__global__ __launch_bounds__(256) void k_gram(const float* __restrict__ x,
                                              float* __restrict__ S1,
                                              float* __restrict__ S2){
  __shared__ __align__(16) unsigned short tile[64*64];
  const int tid  = threadIdx.x;
  const int lane = tid & 63, wave = tid >> 6;
  const int bx   = blockIdx.x;
  const int g = bx >> 7, b = (bx >> 1) & 63, hf = bx & 1;
  const int ck0 = hf ? 25 : 0, ck1 = hf ? 49 : 25;
  const float* xg = x + ((size_t)b*C_ + (size_t)g*NC_) * HW_;
  const int chb = (tid >> 4) * 4;       // this thread's 4 channels: chb+q
  const int posoff = (tid & 15) * 4;
  float s1a[4] = {0.f,0.f,0.f,0.f};
  f32x4 acc[2][2] = {};
  const int wrow = (wave >> 1) * 32, wcol = (wave & 1) * 32;

  for(int ck = ck0; ck < ck1; ++ck){
    const int p0 = ck * 64;
    #pragma unroll
    for(int q = 0; q < 4; ++q){
      const int ch = chb + q;
      const float4 v = *(const float4*)(xg + (size_t)ch*HW_ + p0 + posoff);
      s1a[q] += v.x + v.y + v.z + v.w;
      const unsigned long long pk =
            (unsigned long long)f2bf(v.x)
          | ((unsigned long long)f2bf(v.y) << 16)
          | ((unsigned long long)f2bf(v.z) << 32)
          | ((unsigned long long)f2bf(v.w) << 48);
      *(unsigned long long*)((char*)tile + swz(ch*128 + posoff*2, ch)) = pk;
    }
    __syncthreads();
    #pragma unroll
    for(int ks = 0; ks < 2; ++ks){
      const int kbyte = ks*64 + (lane >> 4) * 16;
      s16x8 a0 = ld_frag(tile, wrow +      (lane & 15), kbyte);
      s16x8 a1 = ld_frag(tile, wrow + 16 + (lane & 15), kbyte);
      s16x8 b0 = ld_frag(tile, wcol +      (lane & 15), kbyte);
      s16x8 b1 = ld_frag(tile, wcol + 16 + (lane & 15), kbyte);
      MFMA_(a0, b0, acc[0][0]);
      MFMA_(a0, b1, acc[0][1]);
      MFMA_(a1, b0, acc[1][0]);
      MFMA_(a1, b1, acc[1][1]);
    }
    __syncthreads();
  }

  float* S2g = S2 + g * (NC_*NC_);
  #pragma unroll
  for(int i = 0; i < 2; ++i)
  #pragma unroll
  for(int j = 0; j < 2; ++j)
  #pragma unroll
  for(int r = 0; r < 4; ++r){
    const int d = wrow + 16*i + (lane >> 4)*4 + r;
    const int e = wcol + 16*j + (lane & 15);
    atomicAdd(&S2g[d*NC_ + e], acc[i][j][r]);
  }
  #pragma unroll
  for(int q = 0; q < 4; ++q){
    float v = s1a[q];
    #pragma unroll
    for(int m2 = 1; m2 < 16; m2 <<= 1) v += __shfl_xor(v, m2, 64);
    if((lane & 15) == 0) atomicAdd(&S1[g*NC_ + chb + q], v);
  }
}

// ---------------- Pass 2: Newton-Schulz ----------------
__device__ __forceinline__ void mm_core(f32x4 acc[2][2],
    const unsigned short* Ah, const unsigned short* Al,
    const unsigned short* Bh, const unsigned short* Bl,
    int lane, int wrow, int wcol){
  #pragma unroll
  for(int ks = 0; ks < 2; ++ks){
    const int kbyte = ks*64 + (lane >> 4) * 16;
    s16x8 ah0 = ld_frag(Ah, wrow +      (lane & 15), kbyte);
    s16x8 ah1 = ld_frag(Ah, wrow + 16 + (lane & 15), kbyte);
    s16x8 al0 = ld_frag(Al, wrow +      (lane & 15), kbyte);
    s16x8 al1 = ld_frag(Al, wrow + 16 + (lane & 15), kbyte);
    s16x8 bh0 = ld_frag(Bh, wcol +      (lane & 15), kbyte);
    s16x8 bh1 = ld_frag(Bh, wcol + 16 + (lane & 15), kbyte);
    s16x8 bl0 = ld_frag(Bl, wcol +      (lane & 15), kbyte);
    s16x8 bl1 = ld_frag(Bl, wcol + 16 + (lane & 15), kbyte);
    MFMA_(ah0, bh0, acc[0][0]); MFMA_(ah0, bl0, acc[0][0]); MFMA_(al0, bh0, acc[0][0]);
    MFMA_(ah0, bh1, acc[0][1]); MFMA_(ah0, bl1, acc[0][1]); MFMA_(al0, bh1, acc[0][1]);
    MFMA_(ah1, bh0, acc[1][0]); MFMA_(ah1, bl0, acc[1][0]); MFMA_(al1, bh0, acc[1][0]);
    MFMA_(ah1, bh1, acc[1][1]); MFMA_(ah1, bl1, acc[1][1]); MFMA_(al1, bh1, acc[1][1]);
  }
}

__device__ __forceinline__ void mm64(unsigned short* dH, unsigned short* dL,
    const unsigned short* Ah, const unsigned short* Al,
    const unsigned short* Bh, const unsigned short* Bl,
    int lane, int wrow, int wcol){
  f32x4 acc[2][2] = {};
  mm_core(acc, Ah, Al, Bh, Bl, lane, wrow, wcol);
  #pragma unroll
  for(int i = 0; i < 2; ++i)
  #pragma unroll
  for(int j = 0; j < 2; ++j)
  #pragma unroll
  for(int r = 0; r < 4; ++r){
    const int d = wrow + 16*i + (lane >> 4)*4 + r;
    const int e = wcol + 16*j + (lane & 15);
    const float v = acc[i][j][r];
    const unsigned short h = f2bf(v);
    st_h(dH, d, e, h);
    st_h(dL, d, e, f2bf(v - bf2f(h)));
  }
}

__device__ __forceinline__ void ns_update(unsigned short* dH, unsigned short* dL,
    const unsigned short* Zh, const unsigned short* Zl,
    const unsigned short* Snh, const unsigned short* Snl,
    const unsigned short* pH, const unsigned short* pL,
    int lane, int wrow, int wcol){
  f32x4 acc[2][2] = {};
  mm_core(acc, Zh, Zl, Snh, Snl, lane, wrow, wcol);
  #pragma unroll
  for(int i = 0; i < 2; ++i)
  #pragma unroll
  for(int j = 0; j < 2; ++j)
  #pragma unroll
  for(int r = 0; r < 4; ++r){
    const int d = wrow + 16*i + (lane >> 4)*4 + r;
    const int e = wcol + 16*j + (lane & 15);
    const float pv = bf2f(ld_h(pH, d, e)) + bf2f(ld_h(pL, d, e));
    const float v = 1.5f*pv - 0.5f*acc[i][j][r];
    const unsigned short h = f2bf(v);
    st_h(dH, d, e, h);
    st_h(dL, d, e, f2bf(v - bf2f(h)));
  }
}

__global__ __launch_bounds__(256) void k_ns(const float* __restrict__ S1,
                                            const float* __restrict__ S2,
                                            float* __restrict__ wm,
                                            float* __restrict__ mu){
  __shared__ __align__(16) unsigned short smem[8*4096];   // 64 KiB exactly
  unsigned short* Snh = smem;
  unsigned short* Snl = smem + 1*4096;
  unsigned short* Xh  = smem + 2*4096;
  unsigned short* Xl  = smem + 3*4096;
  unsigned short* Yh  = smem + 4*4096;
  unsigned short* Yl  = smem + 5*4096;
  unsigned short* Zh  = smem + 6*4096;
  unsigned short* Zl  = smem + 7*4096;
  const int g = blockIdx.x, tid = threadIdx.x;
  const int lane = tid & 63, wave = tid >> 6;
  const float* S1g = S1 + g*NC_;
  const float* S2g = S2 + g*NC_*NC_;
  const float invm = 1.0f / (float)M_;

  // trace of Sigma (every thread redundantly; tiny)
  float tr = 0.f;
  for(int i = 0; i < NC_; ++i){
    const float mui = S1g[i] * invm;
    tr += S2g[i*NC_ + i]*invm - mui*mui + EPS_;
  }
  const float rTr  = 1.0f / tr;
  const float srtr = sqrtf(rTr);

  // Sn = Sigma * rTr (hi/lo), P = I
  {
    const int d  = tid >> 2;
    const int e0 = (tid & 3) * 16;
    const float mud = S1g[d] * invm;
    for(int k = 0; k < 16; ++k){
      const int e = e0 + k;
      const float mue = S1g[e] * invm;
      const float s = (S2g[d*NC_ + e]*invm - mud*mue + ((d==e)?EPS_:0.f)) * rTr;
      const unsigned short h = f2bf(s);
      st_h(Snh, d, e, h);
      st_h(Snl, d, e, f2bf(s - bf2f(h)));
      st_h(Xh,  d, e, (d==e)?(unsigned short)0x3F80:(unsigned short)0);
      st_h(Xl,  d, e, (unsigned short)0);
    }
    if(tid < NC_) mu[g*NC_ + tid] = S1g[tid]*invm;
  }
  __syncthreads();

  unsigned short *pH = Xh, *pL = Xl, *qH = Yh, *qL = Yl;
  const int wrow = (wave >> 1)*32, wcol = (wave & 1)*32;
  for(int it = 0; it < TIT_; ++it){
    mm64(qH, qL, pH, pL, pH, pL, lane, wrow, wcol);     // T1 = P*P
    __syncthreads();
    mm64(Zh, Zl, qH, qL, pH, pL, lane, wrow, wcol);     // T2 = T1*P
    __syncthreads();
    ns_update(qH, qL, Zh, Zl, Snh, Snl, pH, pL, lane, wrow, wcol); // P' into q
    __syncthreads();
    unsigned short* t;
    t = pH; pH = qH; qH = t;
    t = pL; pL = qL; qL = t;
  }

  // wm = P * sqrt(rTr)  (fp32 to global)
  float* wmg = wm + g*NC_*NC_;
  const int d  = tid >> 2;
  const int e0 = (tid & 3) * 16;
  for(int k = 0; k < 16; ++k){
    const int e = e0 + k;
    wmg[d*NC_ + e] = (bf2f(ld_h(pH, d, e)) + bf2f(ld_h(pL, d, e))) * srtr;
  }
}

// ---------------- Pass 3: apply ----------------
__global__ __launch_bounds__(256) void k_apply(const float* __restrict__ x,
                                               const float* __restrict__ wm,
                                               const float* __restrict__ mu,
                                               const float* __restrict__ weight,
                                               const float* __restrict__ bias,
                                               float* __restrict__ out){
  __shared__ __align__(16) unsigned short tile[64*64];
  const int tid  = threadIdx.x;
  const int lane = tid & 63, wave = tid >> 6;
  const int bx   = blockIdx.x;
  const int g = bx >> 7, b = (bx >> 1) & 63, hf = bx & 1;
  const int ck0 = hf ? 25 : 0, ck1 = hf ? 49 : 25;
  const float* xg = x   + ((size_t)b*C_ + (size_t)g*NC_) * HW_;
  float*       og = out + ((size_t)b*C_ + (size_t)g*NC_) * HW_;
  const int chb = (tid >> 4) * 4;
  const int posoff = (tid & 15) * 4;

  float mu4[4];
  #pragma unroll
  for(int q = 0; q < 4; ++q) mu4[q] = mu[g*NC_ + chb + q];

  // wm A-frags (hi/lo) held in registers for this wave's 16 output rows
  const float* wmg = wm + g*NC_*NC_;
  const int arow = wave*16 + (lane & 15);
  s16x8 ah[2], al[2];
  #pragma unroll
  for(int ks = 0; ks < 2; ++ks){
    const int kc = ks*32 + (lane >> 4)*8;
    const float* p = wmg + arow*NC_ + kc;
    #pragma unroll
    for(int j = 0; j < 8; ++j){
      const float v = p[j];
      const unsigned short h = f2bf(v);
      ah[ks][j] = (short)h;
      al[ks][j] = (short)f2bf(v - bf2f(h));
    }
  }
  float wt[4], bsv[4];
  #pragma unroll
  for(int r = 0; r < 4; ++r){
    const int c = g*NC_ + wave*16 + (lane >> 4)*4 + r;
    wt[r]  = weight[c];
    bsv[r] = bias[c];
  }

  for(int ck = ck0; ck < ck1; ++ck){
    const int p0 = ck * 64;
    #pragma unroll
    for(int q = 0; q < 4; ++q){
      const int ch = chb + q;
      const float4 v = *(const float4*)(xg + (size_t)ch*HW_ + p0 + posoff);
      const float m0 = mu4[q];
      const unsigned long long pk =
            (unsigned long long)f2bf(v.x - m0)
          | ((unsigned long long)f2bf(v.y - m0) << 16)
          | ((unsigned long long)f2bf(v.z - m0) << 32)
          | ((unsigned long long)f2bf(v.w - m0) << 48);
      *(unsigned long long*)((char*)tile + swz(ch*128 + posoff*2, ch)) = pk;
    }
    __syncthreads();
    #pragma unroll
    for(int tn = 0; tn < 4; ++tn){
      f32x4 acc = {0.f,0.f,0.f,0.f};
      const int pos = tn*16 + (lane & 15);
      #pragma unroll
      for(int ks = 0; ks < 2; ++ks){
        s16x8 bfr;
        #pragma unroll
        for(int j = 0; j < 8; ++j){
          const int e = ks*32 + (lane >> 4)*8 + j;
          bfr[j] = (short)ld_h(tile, e, pos);
        }
        MFMA_(ah[ks], bfr, acc);
        MFMA_(al[ks], bfr, acc);
      }
      #pragma unroll
      for(int r = 0; r < 4; ++r){
        const int cl = wave*16 + (lane >> 4)*4 + r;
        og[(size_t)cl*HW_ + p0 + pos] = acc[r]*wt[r] + bsv[r];
      }
    }
    __syncthreads();
  }
}

extern "C" void kernel_launch(void* const* d_in, const int* in_sizes, int n_in,
                              void* d_out, int out_size, void* d_ws, size_t ws_size,
                              hipStream_t stream){
  (void)in_sizes; (void)n_in; (void)out_size; (void)ws_size;
  const float* x  = (const float*)d_in[0];
  const float* w  = (const float*)d_in[1];
  const float* bs = (const float*)d_in[2];
  float* out = (float*)d_out;
  float* S1 = (float*)d_ws;            // 256 f
  float* S2 = S1 + 256;                // 4*64*64 f
  float* mu = S2 + G_*NC_*NC_;         // 256 f
  float* wm = mu + 256;                // 4*64*64 f
  hipMemsetAsync(d_ws, 0, (256 + G_*NC_*NC_)*sizeof(float), stream);
  k_gram <<<512, 256, 0, stream>>>(x, S1, S2);
  k_ns   <<<G_,  256, 0, stream>>>(S1, S2, wm, mu);
  k_apply<<<512, 256, 0, stream>>>(x, wm, mu, w, bs, out);
}